// Round 1
// 297.092 us; speedup vs baseline: 1.3224x; 1.3224x over previous
//
#include <hip/hip_runtime.h>

typedef _Float16 f16;
typedef __attribute__((ext_vector_type(4))) _Float16 f16x4;
typedef __attribute__((ext_vector_type(8))) _Float16 f16x8;
typedef __attribute__((ext_vector_type(4))) float f32x4;

#define Tn 4096
#define DHn 64
#define NFn 256
#define BHn 64
#define TCH 64                 // t-rows per chunk
#define NCH 8                  // chunks per block
#define TBLK (TCH * NCH)       // 512 rows per block
#define GRIDX (Tn / TBLK)      // 8
#define KLD 72                 // kLDS/qLDS/vT leading dim (f16), 16B-aligned rows
#define WLDA 72                // kernel A wLDS [nf][t] stride
#define WLDB 264               // kernel B wLDS/ctxLDS [.][nf] stride (256+8)
#define CTXF (65 * NFn)        // floats per bh in ctx (64 dh rows + 1 s row)

static constexpr float DS  = 0.35355339059327379f;  // 64^-0.25 (folded into proj)
static constexpr float DNS = 0.0625f;               // 0.5 * DS^2

// lgkm-only barrier: LDS producer/consumer sync WITHOUT draining vmcnt, so
// prefetched global loads stay in flight across phases (m201 pattern).
#define BAR() do { asm volatile("s_waitcnt lgkmcnt(0)" ::: "memory"); \
                   __builtin_amdgcn_s_barrier(); } while (0)

// ============ Kernel A: ctx[bh][dh][nf] (+ s row) = sum_t kp[t,nf]*[v,1] ============
__global__ __launch_bounds__(256, 2)
void perf_ctx_mfma(const float* __restrict__ K, const float* __restrict__ V,
                   const float* __restrict__ P, float* __restrict__ ctxws,
                   float* __restrict__ part, int use_part)
{
    __shared__ __align__(16) f16 kLDS[TCH * KLD];
    __shared__ __align__(16) f16 vT[DHn * KLD];     // [dh][t], 8-block XOR swizzled
    __shared__ __align__(16) f16 wLDS[NFn * WLDA];  // [nf][t]
    __shared__ float dn[TCH];
    __shared__ __align__(16) float redmax[TCH][4];

    const int bh   = blockIdx.y;
    const int tid  = threadIdx.x;
    const int lane = tid & 63;
    const int wv   = tid >> 6;
    const int c    = lane & 15;
    const int g    = lane >> 4;

    // proj B-frags in regs (DS folded): nf = 64*wv+16*nt+c, dh = 32*kc+8*g+j
    f16x8 pb[4][2];
#pragma unroll
    for (int nt = 0; nt < 4; nt++)
#pragma unroll
        for (int kc = 0; kc < 2; kc++) {
            const float* s = P + (size_t)(64 * wv + 16 * nt + c) * DHn + 32 * kc + 8 * g;
            f16x8 h;
#pragma unroll
            for (int j = 0; j < 8; j++) h[j] = (f16)(s[j] * DS);
            pb[nt][kc] = h;
        }

    f32x4 cacc[4][4];
#pragma unroll
    for (int a = 0; a < 4; a++)
#pragma unroll
        for (int b = 0; b < 4; b++) cacc[a][b] = (f32x4){0.f, 0.f, 0.f, 0.f};
    float sp[4] = {0.f, 0.f, 0.f, 0.f};

    const float* Kb = K + (size_t)bh * Tn * DHn;
    const float* Vb = V + (size_t)bh * Tn * DHn;
    const int rb = 4 * wv + g;   // tid>>4

    // preload chunk 0 into registers
    float4 kq[4], vq[4], kqn[4], vqn[4];
    {
        const int t0 = blockIdx.x * TBLK;
#pragma unroll
        for (int i = 0; i < 4; i++) {
            const int r = 16 * i + rb;
            kq[i] = *(const float4*)(Kb + (size_t)(t0 + r) * DHn + 4 * c);
            vq[i] = *(const float4*)(Vb + (size_t)(t0 + r) * DHn + 4 * c);
        }
    }

    for (int ch = 0; ch < NCH; ch++) {
        // ---- stage current chunk (registers -> LDS) ----
#pragma unroll
        for (int i = 0; i < 4; i++) {
            const int r = 16 * i + rb;
            f16x4 hk;
            hk[0] = (f16)kq[i].x; hk[1] = (f16)kq[i].y;
            hk[2] = (f16)kq[i].z; hk[3] = (f16)kq[i].w;
            *(f16x4*)&kLDS[r * KLD + 4 * c] = hk;
            float p = kq[i].x * kq[i].x + kq[i].y * kq[i].y +
                      kq[i].z * kq[i].z + kq[i].w * kq[i].w;
            p += __shfl_xor(p, 1); p += __shfl_xor(p, 2);
            p += __shfl_xor(p, 4); p += __shfl_xor(p, 8);
            if (c == 0) dn[r] = p * DNS;
            const float* vf = &vq[i].x;
#pragma unroll
            for (int m = 0; m < 4; m++) {
                const int dh = 4 * c + m;
                vT[dh * KLD + ((((r >> 3) ^ ((dh >> 3) & 7)) << 3) | (r & 7))] = (f16)vf[m];
            }
        }
        // ---- issue next chunk's global loads (hidden under GEMM1..GEMM2) ----
        if (ch + 1 < NCH) {
            const int t1 = blockIdx.x * TBLK + (ch + 1) * TCH;
#pragma unroll
            for (int i = 0; i < 4; i++) {
                const int r = 16 * i + rb;
                kqn[i] = *(const float4*)(Kb + (size_t)(t1 + r) * DHn + 4 * c);
                vqn[i] = *(const float4*)(Vb + (size_t)(t1 + r) * DHn + 4 * c);
            }
        }
        BAR();   // S1: staging done

        // GEMM1: dp[t][nf] = K f16 . (DS*proj)^T
        f32x4 dp[4][4];
#pragma unroll
        for (int a = 0; a < 4; a++)
#pragma unroll
            for (int b = 0; b < 4; b++) dp[a][b] = (f32x4){0.f, 0.f, 0.f, 0.f};
#pragma unroll
        for (int mt = 0; mt < 4; mt++) {
            const f16x8 a0 = *(const f16x8*)&kLDS[(16 * mt + c) * KLD + 8 * g];
            const f16x8 a1 = *(const f16x8*)&kLDS[(16 * mt + c) * KLD + 32 + 8 * g];
#pragma unroll
            for (int nt = 0; nt < 4; nt++) {
                dp[mt][nt] = __builtin_amdgcn_mfma_f32_16x16x32_f16(a0, pb[nt][0], dp[mt][nt], 0, 0, 0);
                dp[mt][nt] = __builtin_amdgcn_mfma_f32_16x16x32_f16(a1, pb[nt][1], dp[mt][nt], 0, 0, 0);
            }
        }
        // per-row (t) max over this wave's 64 nf, then cross-wave via LDS
#pragma unroll
        for (int mt = 0; mt < 4; mt++)
#pragma unroll
            for (int r = 0; r < 4; r++) {
                float m = fmaxf(fmaxf(dp[mt][0][r], dp[mt][1][r]),
                                fmaxf(dp[mt][2][r], dp[mt][3][r]));
                m = fmaxf(m, __shfl_xor(m, 1)); m = fmaxf(m, __shfl_xor(m, 2));
                m = fmaxf(m, __shfl_xor(m, 4)); m = fmaxf(m, __shfl_xor(m, 8));
                if (c == 0) redmax[16 * mt + 4 * g + r][wv] = m;
            }
        BAR();   // S2: redmax ready

#pragma unroll
        for (int mt = 0; mt < 4; mt++) {
            float mx[4];
#pragma unroll
            for (int r = 0; r < 4; r++) {
                const int t = 16 * mt + 4 * g + r;
                const f32x4 rm = *(const f32x4*)&redmax[t][0];
                mx[r] = fmaxf(fmaxf(rm[0], rm[1]), fmaxf(rm[2], rm[3])) + dn[t];
            }
#pragma unroll
            for (int nt = 0; nt < 4; nt++) {
                f16x4 hw;
#pragma unroll
                for (int r = 0; r < 4; r++) {
                    const float w = __expf(dp[mt][nt][r] - mx[r]);  // kp (scale/EPS cancel)
                    sp[nt] += w;
                    hw[r] = (f16)w;
                }
                *(f16x4*)&wLDS[(64 * wv + 16 * nt + c) * WLDA + 16 * mt + 4 * g] = hw;
            }
        }
        BAR();   // S3: wLDS ready

        // GEMM2: ctx[nf][dh] += w^T(t->) . V
#pragma unroll
        for (int kc = 0; kc < 2; kc++) {
            f16x8 af[4], bf[4];
#pragma unroll
            for (int mt2 = 0; mt2 < 4; mt2++)
                af[mt2] = *(const f16x8*)&wLDS[(64 * wv + 16 * mt2 + c) * WLDA + 32 * kc + 8 * g];
#pragma unroll
            for (int nt2 = 0; nt2 < 4; nt2++) {
                const int dh = 16 * nt2 + c;
                const int tb = 4 * kc + g;
                bf[nt2] = *(const f16x8*)&vT[dh * KLD + ((tb ^ ((dh >> 3) & 7)) << 3)];
            }
#pragma unroll
            for (int mt2 = 0; mt2 < 4; mt2++)
#pragma unroll
                for (int nt2 = 0; nt2 < 4; nt2++)
                    cacc[mt2][nt2] = __builtin_amdgcn_mfma_f32_16x16x32_f16(
                        af[mt2], bf[nt2], cacc[mt2][nt2], 0, 0, 0);
        }
        BAR();   // Send: protect kLDS/vT for next chunk
#pragma unroll
        for (int i = 0; i < 4; i++) { kq[i] = kqn[i]; vq[i] = vqn[i]; }
    }

    if (use_part) {
        // private per-block partial: plain coalesced stores, no atomics
        float* pb2 = part + (size_t)(bh * GRIDX + blockIdx.x) * CTXF;
#pragma unroll
        for (int mt2 = 0; mt2 < 4; mt2++)
#pragma unroll
            for (int nt2 = 0; nt2 < 4; nt2++)
                *(f32x4*)&pb2[(size_t)(16 * nt2 + c) * NFn + 64 * wv + 16 * mt2 + 4 * g] =
                    cacc[mt2][nt2];
#pragma unroll
        for (int nt = 0; nt < 4; nt++) {
            float sv = sp[nt];
            sv += __shfl_xor(sv, 16); sv += __shfl_xor(sv, 32);
            if (g == 0) pb2[64 * NFn + 64 * wv + 16 * nt + c] = sv;
        }
    } else {
        float* cb = ctxws + (size_t)bh * CTXF;
#pragma unroll
        for (int mt2 = 0; mt2 < 4; mt2++)
#pragma unroll
            for (int nt2 = 0; nt2 < 4; nt2++)
#pragma unroll
                for (int r = 0; r < 4; r++)
                    atomicAdd(&cb[(size_t)(16 * nt2 + c) * NFn + 64 * wv + 16 * mt2 + 4 * g + r],
                              cacc[mt2][nt2][r]);
#pragma unroll
        for (int nt = 0; nt < 4; nt++) {
            float sv = sp[nt];
            sv += __shfl_xor(sv, 16); sv += __shfl_xor(sv, 32);
            if (g == 0) atomicAdd(&cb[64 * NFn + 64 * wv + 16 * nt + c], sv);
        }
    }
}

// ============ Reduce: ctx[bh] = sum over GRIDX partials (streaming, coalesced) ============
__global__ __launch_bounds__(256)
void perf_reduce(const float* __restrict__ part, float* __restrict__ ctxws)
{
    const int bh = blockIdx.y;
    const float* p0 = part + (size_t)bh * GRIDX * CTXF;
    float* cb = ctxws + (size_t)bh * CTXF;
    for (int j = 4 * (threadIdx.x + 256 * blockIdx.x); j < CTXF; j += 4 * 256 * 8) {
        float4 a = *(const float4*)(p0 + j);
#pragma unroll
        for (int s = 1; s < GRIDX; s++) {
            const float4 b4 = *(const float4*)(p0 + (size_t)s * CTXF + j);
            a.x += b4.x; a.y += b4.y; a.z += b4.z; a.w += b4.w;
        }
        *(float4*)(cb + j) = a;
    }
}

// ============ Kernel B: out[t][dh] = (qp . ctx) / (qp . s) ============
__global__ __launch_bounds__(256, 2)
void perf_out_mfma(const float* __restrict__ Q, const float* __restrict__ P,
                   const float* __restrict__ ctxws, float* __restrict__ Out)
{
    __shared__ __align__(16) f16 qLDS[TCH * KLD];
    __shared__ __align__(16) f16 wLDS[TCH * WLDB];    // [t][nf]
    __shared__ __align__(16) f16 ctxLDS[DHn * WLDB];  // [dh][nf]
    __shared__ float sLDS[NFn];
    __shared__ __align__(16) float redmax[TCH][4];
    __shared__ __align__(16) float denP[TCH][4];

    const int bh   = blockIdx.y;
    const int tid  = threadIdx.x;
    const int lane = tid & 63;
    const int wv   = tid >> 6;
    const int c    = lane & 15;
    const int g    = lane >> 4;

    const float* Qb = Q + (size_t)bh * Tn * DHn;
    float* Ob = Out + (size_t)bh * Tn * DHn;
    const int rb = 4 * wv + g;

    // preload chunk 0's Q first (overlaps ctx staging below)
    float4 qv[4], qvn[4];
    {
        const int t0 = blockIdx.x * TBLK;
#pragma unroll
        for (int i = 0; i < 4; i++)
            qv[i] = *(const float4*)(Qb + (size_t)(t0 + 16 * i + rb) * DHn + 4 * c);
    }

    f16x8 pb[4][2];
#pragma unroll
    for (int nt = 0; nt < 4; nt++)
#pragma unroll
        for (int kc = 0; kc < 2; kc++) {
            const float* s = P + (size_t)(64 * wv + 16 * nt + c) * DHn + 32 * kc + 8 * g;
            f16x8 h;
#pragma unroll
            for (int j = 0; j < 8; j++) h[j] = (f16)(s[j] * DS);
            pb[nt][kc] = h;
        }

    // stage ctx (f32 -> f16) and s
    const float* cb = ctxws + (size_t)bh * CTXF;
    {
        const int dh = tid >> 2;
        const int nq = (tid & 3) * 64;
#pragma unroll
        for (int u = 0; u < 16; u++) {
            const float4 cv = *(const float4*)&cb[(size_t)dh * NFn + nq + 4 * u];
            f16x4 h;
            h[0] = (f16)cv.x; h[1] = (f16)cv.y; h[2] = (f16)cv.z; h[3] = (f16)cv.w;
            *(f16x4*)&ctxLDS[dh * WLDB + nq + 4 * u] = h;
        }
        sLDS[tid] = cb[64 * NFn + tid];
    }
    BAR();
    float s4[4];
#pragma unroll
    for (int nt = 0; nt < 4; nt++) s4[nt] = sLDS[64 * wv + 16 * nt + c];

    for (int ch = 0; ch < NCH; ch++) {
        const int t0 = blockIdx.x * TBLK + ch * TCH;
#pragma unroll
        for (int i = 0; i < 4; i++) {
            const int r = 16 * i + rb;
            f16x4 h;
            h[0] = (f16)qv[i].x; h[1] = (f16)qv[i].y;
            h[2] = (f16)qv[i].z; h[3] = (f16)qv[i].w;
            *(f16x4*)&qLDS[r * KLD + 4 * c] = h;
        }
        if (ch + 1 < NCH) {
            const int t1 = blockIdx.x * TBLK + (ch + 1) * TCH;
#pragma unroll
            for (int i = 0; i < 4; i++)
                qvn[i] = *(const float4*)(Qb + (size_t)(t1 + 16 * i + rb) * DHn + 4 * c);
        }
        BAR();   // S1

        f32x4 dp[4][4];
#pragma unroll
        for (int a = 0; a < 4; a++)
#pragma unroll
            for (int b = 0; b < 4; b++) dp[a][b] = (f32x4){0.f, 0.f, 0.f, 0.f};
#pragma unroll
        for (int mt = 0; mt < 4; mt++) {
            const f16x8 a0 = *(const f16x8*)&qLDS[(16 * mt + c) * KLD + 8 * g];
            const f16x8 a1 = *(const f16x8*)&qLDS[(16 * mt + c) * KLD + 32 + 8 * g];
#pragma unroll
            for (int nt = 0; nt < 4; nt++) {
                dp[mt][nt] = __builtin_amdgcn_mfma_f32_16x16x32_f16(a0, pb[nt][0], dp[mt][nt], 0, 0, 0);
                dp[mt][nt] = __builtin_amdgcn_mfma_f32_16x16x32_f16(a1, pb[nt][1], dp[mt][nt], 0, 0, 0);
            }
        }
#pragma unroll
        for (int mt = 0; mt < 4; mt++)
#pragma unroll
            for (int r = 0; r < 4; r++) {
                float m = fmaxf(fmaxf(dp[mt][0][r], dp[mt][1][r]),
                                fmaxf(dp[mt][2][r], dp[mt][3][r]));
                m = fmaxf(m, __shfl_xor(m, 1)); m = fmaxf(m, __shfl_xor(m, 2));
                m = fmaxf(m, __shfl_xor(m, 4)); m = fmaxf(m, __shfl_xor(m, 8));
                if (c == 0) redmax[16 * mt + 4 * g + r][wv] = m;
            }
        BAR();   // S2

#pragma unroll
        for (int mt = 0; mt < 4; mt++) {
            float mx[4], dsum[4];
#pragma unroll
            for (int r = 0; r < 4; r++) {
                const int t = 16 * mt + 4 * g + r;
                const f32x4 rm = *(const f32x4*)&redmax[t][0];
                mx[r] = fmaxf(fmaxf(rm[0], rm[1]), fmaxf(rm[2], rm[3]));
                dsum[r] = 0.f;
            }
#pragma unroll
            for (int nt = 0; nt < 4; nt++)
#pragma unroll
                for (int r = 0; r < 4; r++) {
                    const float w = __expf(dp[mt][nt][r] - mx[r]);  // q-side row factors cancel
                    wLDS[(16 * mt + 4 * g + r) * WLDB + 64 * wv + 16 * nt + c] = (f16)w;
                    dsum[r] += w * s4[nt];
                }
#pragma unroll
            for (int r = 0; r < 4; r++) {
                float d = dsum[r];
                d += __shfl_xor(d, 1); d += __shfl_xor(d, 2);
                d += __shfl_xor(d, 4); d += __shfl_xor(d, 8);
                if (c == 0) denP[16 * mt + 4 * g + r][wv] = d;
            }
        }
        BAR();   // S3

        // GEMM2: out-tile = w . ctx  (wave wv owns t rows [16wv,16wv+16))
        f32x4 oacc[4];
#pragma unroll
        for (int nt2 = 0; nt2 < 4; nt2++) oacc[nt2] = (f32x4){0.f, 0.f, 0.f, 0.f};
#pragma unroll
        for (int kc = 0; kc < 8; kc++) {
            const f16x8 a = *(const f16x8*)&wLDS[(16 * wv + c) * WLDB + 32 * kc + 8 * g];
#pragma unroll
            for (int nt2 = 0; nt2 < 4; nt2++) {
                const f16x8 b = *(const f16x8*)&ctxLDS[(16 * nt2 + c) * WLDB + 32 * kc + 8 * g];
                oacc[nt2] = __builtin_amdgcn_mfma_f32_16x16x32_f16(a, b, oacc[nt2], 0, 0, 0);
            }
        }
#pragma unroll
        for (int r = 0; r < 4; r++) {
            const int t = 16 * wv + 4 * g + r;
            const f32x4 d4 = *(const f32x4*)&denP[t][0];
            const float dinv = __builtin_amdgcn_rcpf(d4[0] + d4[1] + d4[2] + d4[3]);
#pragma unroll
            for (int nt2 = 0; nt2 < 4; nt2++)
                Ob[(size_t)(t0 + t) * DHn + 16 * nt2 + c] = oacc[nt2][r] * dinv;
        }
        BAR();   // Send
#pragma unroll
        for (int i = 0; i < 4; i++) qv[i] = qvn[i];
    }
}

extern "C" void kernel_launch(void* const* d_in, const int* in_sizes, int n_in,
                              void* d_out, int out_size, void* d_ws, size_t ws_size,
                              hipStream_t stream) {
    const float* q    = (const float*)d_in[0];
    const float* k    = (const float*)d_in[1];
    const float* v    = (const float*)d_in[2];
    const float* proj = (const float*)d_in[3];
    float* out = (float*)d_out;
    float* ctx = (float*)d_ws;

    (void)in_sizes; (void)n_in; (void)out_size;

    const size_t ctx_bytes  = (size_t)BHn * CTXF * sizeof(float);            // 4.26 MB
    const size_t part_bytes = (size_t)BHn * GRIDX * CTXF * sizeof(float);    // 34.1 MB
    const int use_part = (ws_size >= ctx_bytes + part_bytes) ? 1 : 0;
    float* part = ctx + (size_t)BHn * CTXF;

    if (!use_part)
        hipMemsetAsync(ctx, 0, ctx_bytes, stream);
    perf_ctx_mfma<<<dim3(GRIDX, BHn), 256, 0, stream>>>(k, v, proj, ctx, part, use_part);
    if (use_part)
        perf_reduce<<<dim3(8, BHn), 256, 0, stream>>>(part, ctx);
    perf_out_mfma<<<dim3(GRIDX, BHn), 256, 0, stream>>>(q, proj, ctx, out);
}

// Round 2
// 268.583 us; speedup vs baseline: 1.4628x; 1.1061x over previous
//
#include <hip/hip_runtime.h>

typedef _Float16 f16;
typedef __attribute__((ext_vector_type(4))) _Float16 f16x4;
typedef __attribute__((ext_vector_type(8))) _Float16 f16x8;
typedef __attribute__((ext_vector_type(4))) float f32x4;

#define Tn 4096
#define DHn 64
#define NFn 256
#define BHn 64
#define TCH 64                 // t-rows per chunk
#define NCH 8                  // chunks per block
#define TBLK (TCH * NCH)       // 512 rows per block
#define GRIDX (Tn / TBLK)      // 8
#define KLD 72                 // kLDS/qLDS/vT leading dim (f16), 16B-aligned rows
#define WLDA 72                // kernel A wLDS [nf][t] stride
#define WLDB 264               // kernel B wLDS/ctxLDS [.][nf] stride (256+8)
#define CTXF (65 * NFn)        // floats per bh in ctx (64 dh rows + 1 s row)

static constexpr float L2E  = 1.4426950408889634f;
static constexpr float DS   = 0.35355339059327379f;   // 64^-0.25 (folded into proj)
static constexpr float DSL  = 0.35355339059327379f * 1.4426950408889634f; // DS*log2e
static constexpr float DNS2 = 0.0625f * 1.4426950408889634f;              // 0.5*DS^2*log2e
static constexpr float SH2  = 12.0f * 1.4426950408889634f;                // const q-shift (log2 dom)

__device__ __forceinline__ float fexp2(float x) { return __builtin_amdgcn_exp2f(x); }

// lgkm-only barrier: LDS producer/consumer sync WITHOUT draining vmcnt, so
// prefetched global loads stay in flight across phases (m201 pattern).
#define BAR() do { asm volatile("s_waitcnt lgkmcnt(0)" ::: "memory"); \
                   __builtin_amdgcn_s_barrier(); } while (0)

// ============ Kernel A: ctx[bh][dh][nf] (+ s row) = sum_t kp[t,nf]*[v,1] ============
__global__ __launch_bounds__(256, 2)
void perf_ctx_mfma(const float* __restrict__ K, const float* __restrict__ V,
                   const float* __restrict__ P, float* __restrict__ ctxws,
                   float* __restrict__ part, int use_part)
{
    __shared__ __align__(16) f16 kLDS[TCH * KLD];
    __shared__ __align__(16) f16 vT[2][DHn * KLD];  // [dbuf][dh][t], 8-block XOR swizzled
    __shared__ __align__(16) f16 wLDS[NFn * WLDA];  // [nf][t]
    __shared__ float dn[TCH];
    __shared__ __align__(16) float redmax[TCH][4];

    const int bh   = blockIdx.y;
    const int tid  = threadIdx.x;
    const int lane = tid & 63;
    const int wv   = tid >> 6;
    const int c    = lane & 15;
    const int g    = lane >> 4;

    // proj B-frags in regs (DS*log2e folded): nf = 64*wv+16*nt+c, dh = 32*kc+8*g+j
    f16x8 pb[4][2];
#pragma unroll
    for (int nt = 0; nt < 4; nt++)
#pragma unroll
        for (int kc = 0; kc < 2; kc++) {
            const float* s = P + (size_t)(64 * wv + 16 * nt + c) * DHn + 32 * kc + 8 * g;
            f16x8 h;
#pragma unroll
            for (int j = 0; j < 8; j++) h[j] = (f16)(s[j] * DSL);
            pb[nt][kc] = h;
        }

    f32x4 cacc[4][4];
#pragma unroll
    for (int a = 0; a < 4; a++)
#pragma unroll
        for (int b = 0; b < 4; b++) cacc[a][b] = (f32x4){0.f, 0.f, 0.f, 0.f};
    float sp[4] = {0.f, 0.f, 0.f, 0.f};

    const float* Kb = K + (size_t)bh * Tn * DHn;
    const float* Vb = V + (size_t)bh * Tn * DHn;
    const int rb = 4 * wv + g;   // tid>>4

    // preload chunk 0 into registers
    float4 kq[4], vq[4], kqn[4], vqn[4];
    {
        const int t0 = blockIdx.x * TBLK;
#pragma unroll
        for (int i = 0; i < 4; i++) {
            const int r = 16 * i + rb;
            kq[i] = *(const float4*)(Kb + (size_t)(t0 + r) * DHn + 4 * c);
            vq[i] = *(const float4*)(Vb + (size_t)(t0 + r) * DHn + 4 * c);
        }
    }

    for (int ch = 0; ch < NCH; ch++) {
        f16* vTc = &vT[ch & 1][0];
        // ---- stage current chunk (registers -> LDS) ----
#pragma unroll
        for (int i = 0; i < 4; i++) {
            const int r = 16 * i + rb;
            f16x4 hk;
            hk[0] = (f16)kq[i].x; hk[1] = (f16)kq[i].y;
            hk[2] = (f16)kq[i].z; hk[3] = (f16)kq[i].w;
            *(f16x4*)&kLDS[r * KLD + 4 * c] = hk;
            float p = kq[i].x * kq[i].x + kq[i].y * kq[i].y +
                      kq[i].z * kq[i].z + kq[i].w * kq[i].w;
            p += __shfl_xor(p, 1); p += __shfl_xor(p, 2);
            p += __shfl_xor(p, 4); p += __shfl_xor(p, 8);
            if (c == 0) dn[r] = p * DNS2;
            const float* vf = &vq[i].x;
#pragma unroll
            for (int m = 0; m < 4; m++) {
                const int dh = 4 * c + m;
                vTc[dh * KLD + ((((r >> 3) ^ ((dh >> 3) & 7)) << 3) | (r & 7))] = (f16)vf[m];
            }
        }
        // ---- issue next chunk's global loads (hidden under GEMM1..GEMM2) ----
        if (ch + 1 < NCH) {
            const int t1 = blockIdx.x * TBLK + (ch + 1) * TCH;
#pragma unroll
            for (int i = 0; i < 4; i++) {
                const int r = 16 * i + rb;
                kqn[i] = *(const float4*)(Kb + (size_t)(t1 + r) * DHn + 4 * c);
                vqn[i] = *(const float4*)(Vb + (size_t)(t1 + r) * DHn + 4 * c);
            }
        }
        BAR();   // S1: staging done

        // GEMM1: dp2[t][nf] = K f16 . (DS*log2e*proj)^T   (log2 domain)
        f32x4 dp[4][4];
#pragma unroll
        for (int a = 0; a < 4; a++)
#pragma unroll
            for (int b = 0; b < 4; b++) dp[a][b] = (f32x4){0.f, 0.f, 0.f, 0.f};
        __builtin_amdgcn_s_setprio(1);
#pragma unroll
        for (int mt = 0; mt < 4; mt++) {
            const f16x8 a0 = *(const f16x8*)&kLDS[(16 * mt + c) * KLD + 8 * g];
            const f16x8 a1 = *(const f16x8*)&kLDS[(16 * mt + c) * KLD + 32 + 8 * g];
#pragma unroll
            for (int nt = 0; nt < 4; nt++) {
                dp[mt][nt] = __builtin_amdgcn_mfma_f32_16x16x32_f16(a0, pb[nt][0], dp[mt][nt], 0, 0, 0);
                dp[mt][nt] = __builtin_amdgcn_mfma_f32_16x16x32_f16(a1, pb[nt][1], dp[mt][nt], 0, 0, 0);
            }
        }
        __builtin_amdgcn_s_setprio(0);
        // per-row (t) max over this wave's 64 nf, then cross-wave via LDS
        // (k-side max must match the reference exactly: it does not cancel)
#pragma unroll
        for (int mt = 0; mt < 4; mt++)
#pragma unroll
            for (int r = 0; r < 4; r++) {
                float m = fmaxf(fmaxf(dp[mt][0][r], dp[mt][1][r]),
                                fmaxf(dp[mt][2][r], dp[mt][3][r]));
                m = fmaxf(m, __shfl_xor(m, 1)); m = fmaxf(m, __shfl_xor(m, 2));
                m = fmaxf(m, __shfl_xor(m, 4)); m = fmaxf(m, __shfl_xor(m, 8));
                if (c == 0) redmax[16 * mt + 4 * g + r][wv] = m;
            }
        BAR();   // S2: redmax ready

#pragma unroll
        for (int mt = 0; mt < 4; mt++) {
            float mx[4];
#pragma unroll
            for (int r = 0; r < 4; r++) {
                const int t = 16 * mt + 4 * g + r;
                const f32x4 rm = *(const f32x4*)&redmax[t][0];
                mx[r] = fmaxf(fmaxf(rm[0], rm[1]), fmaxf(rm[2], rm[3])) + dn[t];
            }
#pragma unroll
            for (int nt = 0; nt < 4; nt++) {
                f16x4 hw;
#pragma unroll
                for (int r = 0; r < 4; r++) {
                    const float w = fexp2(dp[mt][nt][r] - mx[r]);  // kp (scale/EPS cancel)
                    sp[nt] += w;
                    hw[r] = (f16)w;
                }
                *(f16x4*)&wLDS[(64 * wv + 16 * nt + c) * WLDA + 16 * mt + 4 * g] = hw;
            }
        }
        BAR();   // S3: wLDS ready

        // GEMM2: ctx[nf][dh] += w^T(t->) . V
        __builtin_amdgcn_s_setprio(1);
#pragma unroll
        for (int kc = 0; kc < 2; kc++) {
            f16x8 af[4], bf[4];
#pragma unroll
            for (int mt2 = 0; mt2 < 4; mt2++)
                af[mt2] = *(const f16x8*)&wLDS[(64 * wv + 16 * mt2 + c) * WLDA + 32 * kc + 8 * g];
#pragma unroll
            for (int nt2 = 0; nt2 < 4; nt2++) {
                const int dh = 16 * nt2 + c;
                const int tb = 4 * kc + g;
                bf[nt2] = *(const f16x8*)&vTc[dh * KLD + ((tb ^ ((dh >> 3) & 7)) << 3)];
            }
#pragma unroll
            for (int mt2 = 0; mt2 < 4; mt2++)
#pragma unroll
                for (int nt2 = 0; nt2 < 4; nt2++)
                    cacc[mt2][nt2] = __builtin_amdgcn_mfma_f32_16x16x32_f16(
                        af[mt2], bf[nt2], cacc[mt2][nt2], 0, 0, 0);
        }
        __builtin_amdgcn_s_setprio(0);
        // no Send barrier: vT is double-buffered; kLDS/wLDS/dn/redmax protected by S1..S3
#pragma unroll
        for (int i = 0; i < 4; i++) { kq[i] = kqn[i]; vq[i] = vqn[i]; }
    }

    if (use_part) {
        // private per-block partial: plain coalesced stores, no atomics
        float* pb2 = part + (size_t)(bh * GRIDX + blockIdx.x) * CTXF;
#pragma unroll
        for (int mt2 = 0; mt2 < 4; mt2++)
#pragma unroll
            for (int nt2 = 0; nt2 < 4; nt2++)
                *(f32x4*)&pb2[(size_t)(16 * nt2 + c) * NFn + 64 * wv + 16 * mt2 + 4 * g] =
                    cacc[mt2][nt2];
#pragma unroll
        for (int nt = 0; nt < 4; nt++) {
            float sv = sp[nt];
            sv += __shfl_xor(sv, 16); sv += __shfl_xor(sv, 32);
            if (g == 0) pb2[64 * NFn + 64 * wv + 16 * nt + c] = sv;
        }
    } else {
        float* cb = ctxws + (size_t)bh * CTXF;
#pragma unroll
        for (int mt2 = 0; mt2 < 4; mt2++)
#pragma unroll
            for (int nt2 = 0; nt2 < 4; nt2++)
#pragma unroll
                for (int r = 0; r < 4; r++)
                    atomicAdd(&cb[(size_t)(16 * nt2 + c) * NFn + 64 * wv + 16 * mt2 + 4 * g + r],
                              cacc[mt2][nt2][r]);
#pragma unroll
        for (int nt = 0; nt < 4; nt++) {
            float sv = sp[nt];
            sv += __shfl_xor(sv, 16); sv += __shfl_xor(sv, 32);
            if (g == 0) atomicAdd(&cb[64 * NFn + 64 * wv + 16 * nt + c], sv);
        }
    }
}

// ============ Reduce: ctx[bh] = sum over GRIDX partials (streaming, coalesced) ============
__global__ __launch_bounds__(256)
void perf_reduce(const float* __restrict__ part, float* __restrict__ ctxws)
{
    const int bh = blockIdx.y;
    const float* p0 = part + (size_t)bh * GRIDX * CTXF;
    float* cb = ctxws + (size_t)bh * CTXF;
    for (int j = 4 * (threadIdx.x + 256 * blockIdx.x); j < CTXF; j += 4 * 256 * 8) {
        float4 a = *(const float4*)(p0 + j);
#pragma unroll
        for (int s = 1; s < GRIDX; s++) {
            const float4 b4 = *(const float4*)(p0 + (size_t)s * CTXF + j);
            a.x += b4.x; a.y += b4.y; a.z += b4.z; a.w += b4.w;
        }
        *(float4*)(cb + j) = a;
    }
}

// ============ Kernel B: out[t][dh] = (qp . ctx) / (qp . s) ============
// nf columns of wLDS/ctxLDS live in sigma-space: sig(nf) = (nf&~63)|((nf&15)<<2)|((nf>>4)&3).
// MFMA contraction only needs A and B to agree on k-slot order, so a consistent
// permutation is free; it makes the per-chunk w-writes contiguous f16x4 (b64).
__global__ __launch_bounds__(256, 2)
void perf_out_mfma(const float* __restrict__ Q, const float* __restrict__ P,
                   const float* __restrict__ ctxws, float* __restrict__ Out)
{
    __shared__ __align__(16) f16 qLDS[TCH * KLD];
    __shared__ __align__(16) f16 wLDS[TCH * WLDB];    // [t][sig(nf)]
    __shared__ __align__(16) f16 ctxLDS[DHn * WLDB];  // [dh][sig(nf)]
    __shared__ float sLDS[NFn];
    __shared__ __align__(16) float denP[TCH][4];

    const int bh   = blockIdx.y;
    const int tid  = threadIdx.x;
    const int lane = tid & 63;
    const int wv   = tid >> 6;
    const int c    = lane & 15;
    const int g    = lane >> 4;

    const float* Qb = Q + (size_t)bh * Tn * DHn;
    float* Ob = Out + (size_t)bh * Tn * DHn;
    const int rb = 4 * wv + g;

    // preload chunk 0's Q first (overlaps ctx staging below)
    float4 qv[4], qvn[4];
    {
        const int t0 = blockIdx.x * TBLK;
#pragma unroll
        for (int i = 0; i < 4; i++)
            qv[i] = *(const float4*)(Qb + (size_t)(t0 + 16 * i + rb) * DHn + 4 * c);
    }

    f16x8 pb[4][2];
#pragma unroll
    for (int nt = 0; nt < 4; nt++)
#pragma unroll
        for (int kc = 0; kc < 2; kc++) {
            const float* s = P + (size_t)(64 * wv + 16 * nt + c) * DHn + 32 * kc + 8 * g;
            f16x8 h;
#pragma unroll
            for (int j = 0; j < 8; j++) h[j] = (f16)(s[j] * DSL);
            pb[nt][kc] = h;
        }

    // stage ctx (f32 -> f16, sigma-permuted cols) and s (true-space); one-time
    const float* cb = ctxws + (size_t)bh * CTXF;
    {
        const int dh = tid >> 2;
        const int nq = (tid & 3) * 64;
#pragma unroll
        for (int u = 0; u < 16; u++) {
            const float4 cv = *(const float4*)&cb[(size_t)dh * NFn + nq + 4 * u];
            const float* cf = &cv.x;
#pragma unroll
            for (int i = 0; i < 4; i++) {
                const int ct = nq + 4 * u + i;
                const int cs = (ct & ~63) | ((ct & 15) << 2) | ((ct >> 4) & 3);
                ctxLDS[dh * WLDB + cs] = (f16)cf[i];
            }
        }
        sLDS[tid] = cb[64 * NFn + tid];
    }
    BAR();
    float s4[4];
#pragma unroll
    for (int nt = 0; nt < 4; nt++) s4[nt] = sLDS[64 * wv + 16 * nt + c];

    for (int ch = 0; ch < NCH; ch++) {
        const int t0 = blockIdx.x * TBLK + ch * TCH;
#pragma unroll
        for (int i = 0; i < 4; i++) {
            const int r = 16 * i + rb;
            f16x4 h;
            h[0] = (f16)qv[i].x; h[1] = (f16)qv[i].y;
            h[2] = (f16)qv[i].z; h[3] = (f16)qv[i].w;
            *(f16x4*)&qLDS[r * KLD + 4 * c] = h;
        }
        if (ch + 1 < NCH) {
            const int t1 = blockIdx.x * TBLK + (ch + 1) * TCH;
#pragma unroll
            for (int i = 0; i < 4; i++)
                qvn[i] = *(const float4*)(Qb + (size_t)(t1 + 16 * i + rb) * DHn + 4 * c);
        }
        BAR();   // S1

        f32x4 dp[4][4];
#pragma unroll
        for (int a = 0; a < 4; a++)
#pragma unroll
            for (int b = 0; b < 4; b++) dp[a][b] = (f32x4){0.f, 0.f, 0.f, 0.f};
        __builtin_amdgcn_s_setprio(1);
#pragma unroll
        for (int mt = 0; mt < 4; mt++) {
            const f16x8 a0 = *(const f16x8*)&qLDS[(16 * mt + c) * KLD + 8 * g];
            const f16x8 a1 = *(const f16x8*)&qLDS[(16 * mt + c) * KLD + 32 + 8 * g];
#pragma unroll
            for (int nt = 0; nt < 4; nt++) {
                dp[mt][nt] = __builtin_amdgcn_mfma_f32_16x16x32_f16(a0, pb[nt][0], dp[mt][nt], 0, 0, 0);
                dp[mt][nt] = __builtin_amdgcn_mfma_f32_16x16x32_f16(a1, pb[nt][1], dp[mt][nt], 0, 0, 0);
            }
        }
        __builtin_amdgcn_s_setprio(0);

        // softmax w/ constant shift (q-side row factors cancel exactly) — no row max,
        // no cross-wave exchange; w packed f16x4 into sigma-space wLDS.
#pragma unroll
        for (int mt = 0; mt < 4; mt++) {
#pragma unroll
            for (int r = 0; r < 4; r++) {
                const float w0 = fexp2(dp[mt][0][r] - SH2);
                const float w1 = fexp2(dp[mt][1][r] - SH2);
                const float w2 = fexp2(dp[mt][2][r] - SH2);
                const float w3 = fexp2(dp[mt][3][r] - SH2);
                float d = w0 * s4[0] + w1 * s4[1] + w2 * s4[2] + w3 * s4[3];
                d += __shfl_xor(d, 1); d += __shfl_xor(d, 2);
                d += __shfl_xor(d, 4); d += __shfl_xor(d, 8);
                const int t = 16 * mt + 4 * g + r;
                if (c == 0) denP[t][wv] = d;
                f16x4 hw;
                hw[0] = (f16)w0; hw[1] = (f16)w1; hw[2] = (f16)w2; hw[3] = (f16)w3;
                *(f16x4*)&wLDS[t * WLDB + 64 * wv + 4 * c] = hw;
            }
        }
        BAR();   // S3

        // GEMM2: out-tile = w . ctx (sigma k-slots; wave wv owns t rows [16wv,16wv+16))
        f32x4 oacc[4];
#pragma unroll
        for (int nt2 = 0; nt2 < 4; nt2++) oacc[nt2] = (f32x4){0.f, 0.f, 0.f, 0.f};
        __builtin_amdgcn_s_setprio(1);
#pragma unroll
        for (int kc = 0; kc < 8; kc++) {
            const f16x8 a = *(const f16x8*)&wLDS[(16 * wv + c) * WLDB + 32 * kc + 8 * g];
#pragma unroll
            for (int nt2 = 0; nt2 < 4; nt2++) {
                const f16x8 b = *(const f16x8*)&ctxLDS[(16 * nt2 + c) * WLDB + 32 * kc + 8 * g];
                oacc[nt2] = __builtin_amdgcn_mfma_f32_16x16x32_f16(a, b, oacc[nt2], 0, 0, 0);
            }
        }
        __builtin_amdgcn_s_setprio(0);
#pragma unroll
        for (int r = 0; r < 4; r++) {
            const int t = 16 * wv + 4 * g + r;
            const f32x4 d4 = *(const f32x4*)&denP[t][0];
            const float dinv = __builtin_amdgcn_rcpf(d4[0] + d4[1] + d4[2] + d4[3]);
#pragma unroll
            for (int nt2 = 0; nt2 < 4; nt2++)
                Ob[(size_t)(t0 + t) * DHn + 16 * nt2 + c] = oacc[nt2][r] * dinv;
        }
        BAR();   // Send: protect qLDS/wLDS/denP for next chunk
#pragma unroll
        for (int i = 0; i < 4; i++) qv[i] = qvn[i];
    }
}

extern "C" void kernel_launch(void* const* d_in, const int* in_sizes, int n_in,
                              void* d_out, int out_size, void* d_ws, size_t ws_size,
                              hipStream_t stream) {
    const float* q    = (const float*)d_in[0];
    const float* k    = (const float*)d_in[1];
    const float* v    = (const float*)d_in[2];
    const float* proj = (const float*)d_in[3];
    float* out = (float*)d_out;
    float* ctx = (float*)d_ws;

    (void)in_sizes; (void)n_in; (void)out_size;

    const size_t ctx_bytes  = (size_t)BHn * CTXF * sizeof(float);            // 4.26 MB
    const size_t part_bytes = (size_t)BHn * GRIDX * CTXF * sizeof(float);    // 34.1 MB
    const int use_part = (ws_size >= ctx_bytes + part_bytes) ? 1 : 0;
    float* part = ctx + (size_t)BHn * CTXF;

    if (!use_part)
        hipMemsetAsync(ctx, 0, ctx_bytes, stream);
    perf_ctx_mfma<<<dim3(GRIDX, BHn), 256, 0, stream>>>(k, v, proj, ctx, part, use_part);
    if (use_part)
        perf_reduce<<<dim3(8, BHn), 256, 0, stream>>>(part, ctx);
    perf_out_mfma<<<dim3(GRIDX, BHn), 256, 0, stream>>>(q, proj, ctx, out);
}